// Round 4
// baseline (572.756 us; speedup 1.0000x reference)
//
#include <hip/hip_runtime.h>
#include <hip/hip_bf16.h>
#include <stdint.h>
#include <stddef.h>

// Problem dims (fixed): B=64, C=128, H=W=56, 3x3 conv pad=1 stride=1.
#define CH 128
#define HH 56
#define WW 56
#define HWPIX (HH*WW)        // 3136
#define NB 64
#define NPIXF 200704.0f      // B*H*W
#define NCONVBLK 3136        // 64 samples x 49 tiles (8x8 px)

typedef __attribute__((ext_vector_type(8))) short short8v;    // 8 bf16 -> MFMA A/B frag
typedef __attribute__((ext_vector_type(8))) unsigned short bfv8;
typedef __attribute__((ext_vector_type(4))) unsigned short bfv4;
typedef __attribute__((ext_vector_type(4))) float f32x4;

__device__ __forceinline__ unsigned short f2bf(float f) {
  unsigned int u = __float_as_uint(f);
  u += 0x7fffu + ((u >> 16) & 1u);            // RNE
  return (unsigned short)(u >> 16);
}
__device__ __forceinline__ float bf2f(unsigned short s) {
  return __uint_as_float(((unsigned int)s) << 16);
}

// ---------------------------------------------------------------------------
// K1: x NCHW fp32 -> NHWC bf16 (LDS transpose, coalesced 16B/lane writes).
__global__ __launch_bounds__(256)
void prep_x(const float* __restrict__ x, unsigned short* __restrict__ xT) {
  __shared__ unsigned short tile[4 * 56 * 128];
  const int bid = blockIdx.x;
  const int b = bid / 14, hq = bid % 14;
  const int hl = threadIdx.x >> 6;
  const int h = hq * 4 + hl;
  const int w = threadIdx.x & 63;
  if (w < WW) {
    const float* src = x + (size_t)b * CH * HWPIX + h * WW + w;
    const int pos = hl * WW + w;
    #pragma unroll 4
    for (int c0 = 0; c0 < CH; c0 += 8) {
      bfv8 v;
      #pragma unroll
      for (int k = 0; k < 8; ++k) v[k] = f2bf(src[(size_t)(c0 + k) * HWPIX]);
      const int idx = (pos * CH + c0) ^ ((pos & 7) << 3);
      *(bfv8*)(tile + idx) = v;
    }
  }
  __syncthreads();
  unsigned short* out = xT + (size_t)(b * HH + hq * 4) * WW * CH;
  #pragma unroll
  for (int j = 0; j < 14; ++j) {
    const int u = j * 256 + threadIdx.x;
    const int idx = (u * 8) ^ (((u >> 4) & 7) << 3);
    *(bfv8*)(out + u * 8) = *(const bfv8*)(tile + idx);
  }
}

// ---------------------------------------------------------------------------
// K2: weights [B,O,I,3,3] fp32 -> [B,tap,O,I] bf16 (dense reads, 16B writes).
__global__ __launch_bounds__(256)
void prep_w(const float* __restrict__ w1, const float* __restrict__ w2,
            unsigned short* __restrict__ o1, unsigned short* __restrict__ o2) {
  __shared__ unsigned short lw[18432];
  const int id = blockIdx.x;
  const int which = id >> 9;
  const int b = (id >> 3) & 63, ck = id & 7;
  const float* src = (which ? w2 : w1) + ((size_t)b * 16384 + ck * 2048) * 9;
  unsigned short* dst = (which ? o2 : o1);
  const int t = threadIdx.x;
  #pragma unroll
  for (int j = 0; j < 72; ++j)
    lw[j * 256 + t] = f2bf(src[j * 256 + t]);
  __syncthreads();
  const int ol = t >> 4, oct = t & 15;
  #pragma unroll
  for (int tap = 0; tap < 9; ++tap) {
    bfv8 v;
    #pragma unroll
    for (int k = 0; k < 8; ++k) v[k] = lw[(ol * 128 + oct * 8 + k) * 9 + tap];
    *(bfv8*)(dst + ((size_t)(b * 9 + tap) * CH + ck * 16 + ol) * CH + oct * 8) = v;
  }
}

// ---------------------------------------------------------------------------
// K3/K5: per-sample conv, implicit GEMM.
// R12: O-SPLIT RESTRUCTURE. launch_bounds sweep (R10/R11) proved the natural
// combined register need (~180/wave) is what caps occupancy at 2 waves/SIMD;
// forcing smaller budgets spills (FETCH 34->129/171MB = fatal). So shrink the
// need structurally: 512 threads / 8 waves, each wave owns 16 output channels
// (was 4 waves x 32): acc 32->16 regs, weight bufs 32->16 regs, -32 regs/wave.
// Natural need ~116 <= 128 = the (512,4) budget -> 2 blocks/CU = 4 waves/SIMD
// WITHOUT spill. Weight L2 traffic/block unchanged (8 waves cover 128 O-rows
// once). LDS B-frag reads double (~50-70% LDS pipe) - acceptable for 2x TLP.
// Predict: VGPR ~96-112, FETCH ~35MB (inflation = spill = abort), occ ~45%,
// MfmaUtil ~26, conv ~100-115us.
template<bool FUSE>
__global__ __launch_bounds__(512, 4)
void conv_kernel(const unsigned short* __restrict__ in,
                 const unsigned short* __restrict__ wt,
                 unsigned short* __restrict__ outp,
                 float* __restrict__ partials,
                 const float* __restrict__ tab) {   // [256]: scale | shift (FUSE)
  __shared__ unsigned short patch[100 * 136];
  __shared__ float sacc[256];                       // sum[128] | sumsq[128]
  const int xcd = blockIdx.x & 7;
  const int q = blockIdx.x >> 3;                    // 0..391
  const int s = q / 49;
  const int tile = q - s * 49;
  const int b = s * 8 + xcd;
  const int ty = tile / 7, tx = tile % 7;
  const int h0 = ty * 8, w0 = tx * 8;
  const int t = threadIdx.x;

  const int lane = t & 63, wv = t >> 6;             // wv 0..7
  const int lrow = lane & 15, lgrp = lane >> 4;
  const int px = lrow & 7, pyl = lrow >> 3;

  if (t < 256) sacc[t] = 0.0f;

  // A: lane holds W[o = wv*16 + lrow][k]; half I covers k-chunk
  // (I%2)*64 + c2*32 + lgrp*8.
  const unsigned short* wbase =
      wt + (size_t)b * 9 * CH * CH + (wv * 16 + lrow) * CH + lgrp * 8;

  short8v b0[2], b1[2];
#define LOAD_HALF(dst, I) { \
    const unsigned short* wtap_ = wbase + ((I) / 2) * CH * CH + ((I) % 2) * 64; \
    dst[0] = *(const short8v*)(wtap_); \
    dst[1] = *(const short8v*)(wtap_ + 32); }

  // Head start: first two halves in flight before/through the staging barrier.
  LOAD_HALF(b0, 0)
  LOAD_HALF(b1, 1)

  if (t < 400) {                                    // 100 rows x 4 quarters of 32ch
    const int row = t >> 2, qtr = t & 3;
    const int dh = row / 10, dw = row - dh * 10;
    const int h = h0 + dh - 1, w = w0 + dw - 1;
    unsigned short* ld = &patch[row * 136 + qtr * 32];
    if (h >= 0 && h < HH && w >= 0 && w < WW) {
      const unsigned short* src = in + ((size_t)((b * HH + h) * WW + w)) * CH + qtr * 32;
      if (FUSE) {
        #pragma unroll
        for (int j = 0; j < 4; ++j) {
          const bfv8 v = *(const bfv8*)(src + j * 8);
          bfv8 o;
          #pragma unroll
          for (int k = 0; k < 8; ++k) {
            const int c = qtr * 32 + j * 8 + k;
            const float f = fmaxf(bf2f(v[k]) * tab[c] + tab[CH + c], 0.0f);
            o[k] = f2bf(f);
          }
          *(bfv8*)(ld + j * 8) = o;
        }
      } else {
        #pragma unroll
        for (int j = 0; j < 4; ++j)
          *(bfv8*)(ld + j * 8) = *(const bfv8*)(src + j * 8);
      }
    } else {
      const bfv8 z = {0, 0, 0, 0, 0, 0, 0, 0};
      #pragma unroll
      for (int j = 0; j < 4; ++j) *(bfv8*)(ld + j * 8) = z;
    }
  }
  __syncthreads();

  f32x4 acc[4];
  #pragma unroll
  for (int n = 0; n < 4; ++n) acc[n] = (f32x4){0.f, 0.f, 0.f, 0.f};

#define MFMA_HALF(src, I) { \
    const int posb_ = (pyl + ((I) / 2) / 3) * 10 + px + ((I) / 2) % 3; \
    _Pragma("unroll") \
    for (int c2 = 0; c2 < 2; ++c2) { \
      _Pragma("unroll") \
      for (int nf = 0; nf < 4; ++nf) { \
        const short8v bfr = \
            *(const short8v*)(&patch[(posb_ + nf * 20) * 136 + (((I) % 2) * 2 + c2) * 32 + lgrp * 8]); \
        acc[nf] = __builtin_amdgcn_mfma_f32_16x16x32_bf16(src[c2], bfr, acc[nf], 0, 0, 0); \
      } } }

  // 18 half-taps, depth-1 lookahead over 2 rotating buffers.
  MFMA_HALF(b0,  0) LOAD_HALF(b0,  2)
  MFMA_HALF(b1,  1) LOAD_HALF(b1,  3)
  MFMA_HALF(b0,  2) LOAD_HALF(b0,  4)
  MFMA_HALF(b1,  3) LOAD_HALF(b1,  5)
  MFMA_HALF(b0,  4) LOAD_HALF(b0,  6)
  MFMA_HALF(b1,  5) LOAD_HALF(b1,  7)
  MFMA_HALF(b0,  6) LOAD_HALF(b0,  8)
  MFMA_HALF(b1,  7) LOAD_HALF(b1,  9)
  MFMA_HALF(b0,  8) LOAD_HALF(b0, 10)
  MFMA_HALF(b1,  9) LOAD_HALF(b1, 11)
  MFMA_HALF(b0, 10) LOAD_HALF(b0, 12)
  MFMA_HALF(b1, 11) LOAD_HALF(b1, 13)
  MFMA_HALF(b0, 12) LOAD_HALF(b0, 14)
  MFMA_HALF(b1, 13) LOAD_HALF(b1, 15)
  MFMA_HALF(b0, 14) LOAD_HALF(b0, 16)
  MFMA_HALF(b1, 15) LOAD_HALF(b1, 17)
  MFMA_HALF(b0, 16)
  MFMA_HALF(b1, 17)
#undef LOAD_HALF
#undef MFMA_HALF

  __syncthreads();   // patch reads done everywhere; reuse patch as output buffer

  // Stage D into LDS: obuf[pixel p 0..63][ch 0..127] bf16, byte ^= ((p&3)<<5).
  char* obuf = (char*)patch;
  #pragma unroll
  for (int nf = 0; nf < 4; ++nf) {
    const f32x4 v = acc[nf];
    bfv4 pk;
    #pragma unroll
    for (int r = 0; r < 4; ++r) pk[r] = f2bf(v[r]);
    const int p = (nf * 2 + pyl) * 8 + px;
    const int ch = wv * 16 + lgrp * 4;
    int byte = p * 256 + ch * 2;
    byte ^= ((byte >> 8) & 3) << 5;
    *(bfv4*)(obuf + byte) = pk;
  }

  // Fused BN stat partials: shuffle-reduce over the 16 pixel-row lanes,
  // LDS-accumulate (unique (wv,lgrp,r) -> unique channel), then one
  // non-atomic 256-float row per block.
  {
    f32x4 sv4 = {0.f, 0.f, 0.f, 0.f}, qv4 = {0.f, 0.f, 0.f, 0.f};
    #pragma unroll
    for (int nf = 0; nf < 4; ++nf) {
      const f32x4 v = acc[nf];
      sv4 += v;
      qv4 += v * v;
    }
    #pragma unroll
    for (int r = 0; r < 4; ++r) {
      float sv = sv4[r], qv = qv4[r];
      sv += __shfl_xor(sv, 1, 64);  qv += __shfl_xor(qv, 1, 64);
      sv += __shfl_xor(sv, 2, 64);  qv += __shfl_xor(qv, 2, 64);
      sv += __shfl_xor(sv, 4, 64);  qv += __shfl_xor(qv, 4, 64);
      sv += __shfl_xor(sv, 8, 64);  qv += __shfl_xor(qv, 8, 64);
      if (lrow == 0) {
        const int ch = wv * 16 + lgrp * 4 + r;
        atomicAdd(&sacc[ch], sv);        // unique writer per channel
        atomicAdd(&sacc[CH + ch], qv);
      }
    }
  }

  __syncthreads();

  if (t < 256) partials[(size_t)blockIdx.x * 256 + t] = sacc[t];

  // Copy out: 2 passes x 512 threads x 16B, contiguous per wave.
  #pragma unroll
  for (int j = 0; j < 2; ++j) {
    const int u = j * 512 + t;           // 16B unit index, 0..1023
    int byte = u * 16;
    byte ^= ((byte >> 8) & 3) << 5;
    const bfv8 v = *(const bfv8*)(obuf + byte);
    const int pix = u >> 4, py = pix >> 3, pxx = pix & 7;
    *(bfv8*)(outp + ((size_t)((b * HH + h0 + py) * WW + (w0 + pxx))) * CH +
             (u & 15) * 8) = v;
  }
}

// ---------------------------------------------------------------------------
// K-red: reduce partials[3136][256] -> st[256]. 32 blocks x 256 thr.
__global__ __launch_bounds__(256)
void stat_reduce(const float* __restrict__ partials, float* __restrict__ st) {
  const int t = threadIdx.x;
  float s = 0.0f;
  const int i0 = blockIdx.x * (NCONVBLK / 32);
  for (int i = 0; i < NCONVBLK / 32; ++i)
    s += partials[(size_t)(i0 + i) * 256 + t];
  atomicAdd(&st[t], s);
}

// ---------------------------------------------------------------------------
// K4/K6: per-channel BN stats -> scale/shift tables.
__global__ __launch_bounds__(128)
void bn_stats(const float* __restrict__ st, const float* __restrict__ gamma,
              const float* __restrict__ beta, float* __restrict__ tab) {
  const int c = threadIdx.x;
  const float inv = 1.0f / NPIXF;
  const float mean = st[c] * inv;
  const float var = st[CH + c] * inv - mean * mean;
  const float s = gamma[c] / sqrtf(var + 1e-5f);
  tab[c] = s;
  tab[CH + c] = beta[c] - mean * s;
}

// ---------------------------------------------------------------------------
// K7: out = relu(scale2*y2 + shift2 + residual), NHWC bf16 -> NCHW fp32.
// BF16RES: residual from xT (bf16 NHWC, 51MB) instead of x (fp32 NCHW, 205MB).
template<bool BF16RES>
__global__ __launch_bounds__(256)
void final_kernel(const unsigned short* __restrict__ y2,
                  const unsigned short* __restrict__ xbf,
                  const float* __restrict__ x,
                  const float* __restrict__ tab, float* __restrict__ out) {
  const int bid = blockIdx.x;
  const int b = bid / 14, hq = bid % 14;
  const int h = hq * 4 + (threadIdx.x >> 6);
  const int w = threadIdx.x & 63;
  if (w >= WW) return;
  const unsigned short* ys = y2 + ((size_t)(b * HH + h) * WW + w) * CH;
  const unsigned short* rs = xbf + ((size_t)(b * HH + h) * WW + w) * CH;
  const float* xs = x + (size_t)b * CH * HWPIX + h * WW + w;
  float* os = out + (size_t)b * CH * HWPIX + h * WW + w;
  #pragma unroll 4
  for (int c = 0; c < CH; ++c) {
    const float v = bf2f(ys[c]);
    const float res = BF16RES ? bf2f(rs[c]) : xs[(size_t)c * HWPIX];
    const float r = v * tab[c] + tab[CH + c] + res;
    os[(size_t)c * HWPIX] = fmaxf(r, 0.0f);
  }
}

// ---------------------------------------------------------------------------
extern "C" void kernel_launch(void* const* d_in, const int* in_sizes, int n_in,
                              void* d_out, int out_size, void* d_ws, size_t ws_size,
                              hipStream_t stream) {
  const float* x  = (const float*)d_in[0];
  const float* w1 = (const float*)d_in[1];
  const float* w2 = (const float*)d_in[2];
  const float* g1 = (const float*)d_in[3];
  const float* b1 = (const float*)d_in[4];
  const float* g2 = (const float*)d_in[5];
  const float* b2 = (const float*)d_in[6];
  float* out = (float*)d_out;

  // Workspace layout (bytes):
  //   xT   0            51,380,224
  //   y1   51,380,224   51,380,224
  //   w1b  102,760,448  18,874,368
  //   w2b  121,634,816  18,874,368
  //   p1   140,509,184  3,211,264
  //   p2   143,720,448  3,211,264
  //   st   146,931,712  4,096   (st1|st2|tab1|tab2, 256 floats each)
  //   y2   146,935,808  51,380,224  (optional, if ws_size allows)
  char* ws = (char*)d_ws;
  unsigned short* xT  = (unsigned short*)(ws);
  unsigned short* y1  = (unsigned short*)(ws + 51380224);
  unsigned short* w1b = (unsigned short*)(ws + 102760448);
  unsigned short* w2b = (unsigned short*)(ws + 121634816);
  float*          p1  = (float*)(ws + 140509184);
  float*          p2  = (float*)(ws + 143720448);
  float*          st  = (float*)(ws + 146931712);
  const bool sepY2 = ws_size >= (size_t)146935808 + 51380224;
  unsigned short* y2  = sepY2 ? (unsigned short*)(ws + 146935808) : xT;

  (void)hipMemsetAsync(st, 0, 2048, stream);  // zero st1+st2

  hipLaunchKernelGGL(prep_x, dim3(NB * 14), dim3(256), 0, stream, x, xT);
  hipLaunchKernelGGL(prep_w, dim3(1024), dim3(256), 0, stream, w1, w2, w1b, w2b);
  hipLaunchKernelGGL((conv_kernel<false>), dim3(NCONVBLK), dim3(512), 0, stream,
                     xT, w1b, y1, p1, (const float*)nullptr);
  hipLaunchKernelGGL(stat_reduce, dim3(32), dim3(256), 0, stream, p1, st);
  hipLaunchKernelGGL(bn_stats, dim3(1), dim3(128), 0, stream, st, g1, b1, st + 512);
  hipLaunchKernelGGL((conv_kernel<true>), dim3(NCONVBLK), dim3(512), 0, stream,
                     y1, w2b, y2, p2, st + 512);
  hipLaunchKernelGGL(stat_reduce, dim3(32), dim3(256), 0, stream, p2, st + 256);
  hipLaunchKernelGGL(bn_stats, dim3(1), dim3(128), 0, stream, st + 256, g2, b2, st + 768);
  if (sepY2) {
    hipLaunchKernelGGL((final_kernel<true>), dim3(NB * 14), dim3(256), 0, stream,
                       y2, xT, x, st + 768, out);
  } else {
    hipLaunchKernelGGL((final_kernel<false>), dim3(NB * 14), dim3(256), 0, stream,
                       y2, xT, x, st + 768, out);
  }
}

// Round 5
// 495.128 us; speedup vs baseline: 1.1568x; 1.1568x over previous
//
#include <hip/hip_runtime.h>
#include <hip/hip_bf16.h>
#include <stdint.h>
#include <stddef.h>

// Problem dims (fixed): B=64, C=128, H=W=56, 3x3 conv pad=1 stride=1.
#define CH 128
#define HH 56
#define WW 56
#define HWPIX (HH*WW)        // 3136
#define NB 64
#define NPIXF 200704.0f      // B*H*W
#define NCONVBLK 3136        // per-och-half block count (64 samples x 49 tiles)
#define NCONVGRID 6272       // x2 output-channel halves

typedef __attribute__((ext_vector_type(8))) short short8v;    // 8 bf16 -> MFMA A/B frag
typedef __attribute__((ext_vector_type(8))) unsigned short bfv8;
typedef __attribute__((ext_vector_type(4))) unsigned short bfv4;
typedef __attribute__((ext_vector_type(4))) float f32x4;

__device__ __forceinline__ unsigned short f2bf(float f) {
  unsigned int u = __float_as_uint(f);
  u += 0x7fffu + ((u >> 16) & 1u);            // RNE
  return (unsigned short)(u >> 16);
}
__device__ __forceinline__ float bf2f(unsigned short s) {
  return __uint_as_float(((unsigned int)s) << 16);
}

// ---------------------------------------------------------------------------
// K1: x NCHW fp32 -> NHWC bf16 (LDS transpose, coalesced 16B/lane writes).
__global__ __launch_bounds__(256)
void prep_x(const float* __restrict__ x, unsigned short* __restrict__ xT) {
  __shared__ unsigned short tile[4 * 56 * 128];
  const int bid = blockIdx.x;
  const int b = bid / 14, hq = bid % 14;
  const int hl = threadIdx.x >> 6;
  const int h = hq * 4 + hl;
  const int w = threadIdx.x & 63;
  if (w < WW) {
    const float* src = x + (size_t)b * CH * HWPIX + h * WW + w;
    const int pos = hl * WW + w;
    #pragma unroll 4
    for (int c0 = 0; c0 < CH; c0 += 8) {
      bfv8 v;
      #pragma unroll
      for (int k = 0; k < 8; ++k) v[k] = f2bf(src[(size_t)(c0 + k) * HWPIX]);
      const int idx = (pos * CH + c0) ^ ((pos & 7) << 3);
      *(bfv8*)(tile + idx) = v;
    }
  }
  __syncthreads();
  unsigned short* out = xT + (size_t)(b * HH + hq * 4) * WW * CH;
  #pragma unroll
  for (int j = 0; j < 14; ++j) {
    const int u = j * 256 + threadIdx.x;
    const int idx = (u * 8) ^ (((u >> 4) & 7) << 3);
    *(bfv8*)(out + u * 8) = *(const bfv8*)(tile + idx);
  }
}

// ---------------------------------------------------------------------------
// K2: weights [B,O,I,3,3] fp32 -> [B,tap,O,I] bf16 (dense reads, 16B writes).
__global__ __launch_bounds__(256)
void prep_w(const float* __restrict__ w1, const float* __restrict__ w2,
            unsigned short* __restrict__ o1, unsigned short* __restrict__ o2) {
  __shared__ unsigned short lw[18432];
  const int id = blockIdx.x;
  const int which = id >> 9;
  const int b = (id >> 3) & 63, ck = id & 7;
  const float* src = (which ? w2 : w1) + ((size_t)b * 16384 + ck * 2048) * 9;
  unsigned short* dst = (which ? o2 : o1);
  const int t = threadIdx.x;
  #pragma unroll
  for (int j = 0; j < 72; ++j)
    lw[j * 256 + t] = f2bf(src[j * 256 + t]);
  __syncthreads();
  const int ol = t >> 4, oct = t & 15;
  #pragma unroll
  for (int tap = 0; tap < 9; ++tap) {
    bfv8 v;
    #pragma unroll
    for (int k = 0; k < 8; ++k) v[k] = lw[(ol * 128 + oct * 8 + k) * 9 + tap];
    *(bfv8*)(dst + ((size_t)(b * 9 + tap) * CH + ck * 16 + ol) * CH + oct * 8) = v;
  }
}

// ---------------------------------------------------------------------------
// K3/K5: per-sample conv, implicit GEMM.
// R13: O-split at 256 threads. History: natural combined reg need of the
// 32-O-per-wave structure is ~180 -> 2 waves/SIMD (155us, R8). Forcing
// smaller budgets spills (R10/R11/R12: FETCH 34->129/171/205MB = fatal).
// R12 (512thr, budget 128) proved -32 regs structurally isn't enough for a
// 128 budget. Here: 4 waves x 16 O-channels (acc[4]=16, b0/b1[2]=16, -32
// vs R8), block covers 64 O-ch; tile's other half -> a second block
// (grid 6272; duplicate patch staging is L3-resident, ~free on HBM).
// Estimated need ~148 < 168 = (256,3) budget -> 3 blocks/CU spill-free.
// Predict: VGPR 90-130, FETCH ~40MB (>60MB = spill = abort), occ 30-38%,
// MfmaUtil 19-25, conv 115-135us.
template<bool FUSE>
__global__ __launch_bounds__(256, 3)
void conv_kernel(const unsigned short* __restrict__ in,
                 const unsigned short* __restrict__ wt,
                 unsigned short* __restrict__ outp,
                 float* __restrict__ partials,
                 const float* __restrict__ tab) {   // [256]: scale | shift (FUSE)
  __shared__ unsigned short patch[100 * 136];
  __shared__ float sacc[128];                       // sum[64] | sumsq[64] (local)
  const int xcd = blockIdx.x & 7;
  const int q2 = blockIdx.x >> 3;                   // 0..783
  const int och = q2 & 1;                           // which 64-ch output half
  const int q = q2 >> 1;                            // 0..391
  const int s = q / 49;
  const int tile = q - s * 49;
  const int b = s * 8 + xcd;
  const int ty = tile / 7, tx = tile % 7;
  const int h0 = ty * 8, w0 = tx * 8;
  const int t = threadIdx.x;

  const int lane = t & 63, wv = t >> 6;             // wv 0..3
  const int lrow = lane & 15, lgrp = lane >> 4;
  const int px = lrow & 7, pyl = lrow >> 3;

  if (t < 128) sacc[t] = 0.0f;

  // A: lane holds W[o = och*64 + wv*16 + lrow][k]; half I covers k-chunk
  // (I%2)*64 + c2*32 + lgrp*8.
  const unsigned short* wbase =
      wt + (size_t)b * 9 * CH * CH + (och * 64 + wv * 16 + lrow) * CH + lgrp * 8;

  short8v b0[2], b1[2];
#define LOAD_HALF(dst, I) { \
    const unsigned short* wtap_ = wbase + ((I) / 2) * CH * CH + ((I) % 2) * 64; \
    dst[0] = *(const short8v*)(wtap_); \
    dst[1] = *(const short8v*)(wtap_ + 32); }

  // Head start: first two halves in flight before/through the staging barrier.
  LOAD_HALF(b0, 0)
  LOAD_HALF(b1, 1)

  if (t < 200) {                                    // 100 rows x 2 halves of 64ch
    const int row = t >> 1, half = t & 1;
    const int dh = row / 10, dw = row - dh * 10;
    const int h = h0 + dh - 1, w = w0 + dw - 1;
    unsigned short* ld = &patch[row * 136 + half * 64];
    if (h >= 0 && h < HH && w >= 0 && w < WW) {
      const unsigned short* src = in + ((size_t)((b * HH + h) * WW + w)) * CH + half * 64;
      if (FUSE) {
        #pragma unroll
        for (int j = 0; j < 8; ++j) {
          const bfv8 v = *(const bfv8*)(src + j * 8);
          bfv8 o;
          #pragma unroll
          for (int k = 0; k < 8; ++k) {
            const int c = half * 64 + j * 8 + k;
            const float f = fmaxf(bf2f(v[k]) * tab[c] + tab[CH + c], 0.0f);
            o[k] = f2bf(f);
          }
          *(bfv8*)(ld + j * 8) = o;
        }
      } else {
        #pragma unroll
        for (int j = 0; j < 8; ++j)
          *(bfv8*)(ld + j * 8) = *(const bfv8*)(src + j * 8);
      }
    } else {
      const bfv8 z = {0, 0, 0, 0, 0, 0, 0, 0};
      #pragma unroll
      for (int j = 0; j < 8; ++j) *(bfv8*)(ld + j * 8) = z;
    }
  }
  __syncthreads();

  f32x4 acc[4];
  #pragma unroll
  for (int n = 0; n < 4; ++n) acc[n] = (f32x4){0.f, 0.f, 0.f, 0.f};

#define MFMA_HALF(src, I) { \
    const int posb_ = (pyl + ((I) / 2) / 3) * 10 + px + ((I) / 2) % 3; \
    _Pragma("unroll") \
    for (int c2 = 0; c2 < 2; ++c2) { \
      _Pragma("unroll") \
      for (int nf = 0; nf < 4; ++nf) { \
        const short8v bfr = \
            *(const short8v*)(&patch[(posb_ + nf * 20) * 136 + (((I) % 2) * 2 + c2) * 32 + lgrp * 8]); \
        acc[nf] = __builtin_amdgcn_mfma_f32_16x16x32_bf16(src[c2], bfr, acc[nf], 0, 0, 0); \
      } } }

  // 18 half-taps, depth-1 lookahead over 2 rotating buffers.
  MFMA_HALF(b0,  0) LOAD_HALF(b0,  2)
  MFMA_HALF(b1,  1) LOAD_HALF(b1,  3)
  MFMA_HALF(b0,  2) LOAD_HALF(b0,  4)
  MFMA_HALF(b1,  3) LOAD_HALF(b1,  5)
  MFMA_HALF(b0,  4) LOAD_HALF(b0,  6)
  MFMA_HALF(b1,  5) LOAD_HALF(b1,  7)
  MFMA_HALF(b0,  6) LOAD_HALF(b0,  8)
  MFMA_HALF(b1,  7) LOAD_HALF(b1,  9)
  MFMA_HALF(b0,  8) LOAD_HALF(b0, 10)
  MFMA_HALF(b1,  9) LOAD_HALF(b1, 11)
  MFMA_HALF(b0, 10) LOAD_HALF(b0, 12)
  MFMA_HALF(b1, 11) LOAD_HALF(b1, 13)
  MFMA_HALF(b0, 12) LOAD_HALF(b0, 14)
  MFMA_HALF(b1, 13) LOAD_HALF(b1, 15)
  MFMA_HALF(b0, 14) LOAD_HALF(b0, 16)
  MFMA_HALF(b1, 15) LOAD_HALF(b1, 17)
  MFMA_HALF(b0, 16)
  MFMA_HALF(b1, 17)
#undef LOAD_HALF
#undef MFMA_HALF

  __syncthreads();   // patch reads done everywhere; reuse patch as output buffer

  // Stage D into LDS: obuf[pixel p 0..63][local ch 0..63] bf16, 128B rows,
  // byte ^= ((p&7)<<4)  (verified: writes 2-way max, copy-out reads clean).
  char* obuf = (char*)patch;
  #pragma unroll
  for (int nf = 0; nf < 4; ++nf) {
    const f32x4 v = acc[nf];
    bfv4 pk;
    #pragma unroll
    for (int r = 0; r < 4; ++r) pk[r] = f2bf(v[r]);
    const int p = (nf * 2 + pyl) * 8 + px;
    const int lch = wv * 16 + lgrp * 4;
    int byte = p * 128 + lch * 2;
    byte ^= (p & 7) << 4;
    *(bfv4*)(obuf + byte) = pk;
  }

  // Fused BN stat partials: shuffle-reduce over the 16 pixel lanes,
  // LDS-accumulate (unique (wv,lgrp,r) -> unique local channel), then one
  // non-atomic 128-float row per block.
  {
    f32x4 sv4 = {0.f, 0.f, 0.f, 0.f}, qv4 = {0.f, 0.f, 0.f, 0.f};
    #pragma unroll
    for (int nf = 0; nf < 4; ++nf) {
      const f32x4 v = acc[nf];
      sv4 += v;
      qv4 += v * v;
    }
    #pragma unroll
    for (int r = 0; r < 4; ++r) {
      float sv = sv4[r], qv = qv4[r];
      sv += __shfl_xor(sv, 1, 64);  qv += __shfl_xor(qv, 1, 64);
      sv += __shfl_xor(sv, 2, 64);  qv += __shfl_xor(qv, 2, 64);
      sv += __shfl_xor(sv, 4, 64);  qv += __shfl_xor(qv, 4, 64);
      sv += __shfl_xor(sv, 8, 64);  qv += __shfl_xor(qv, 8, 64);
      if (lrow == 0) {
        const int lch = wv * 16 + lgrp * 4 + r;
        atomicAdd(&sacc[lch], sv);        // unique writer per local channel
        atomicAdd(&sacc[64 + lch], qv);
      }
    }
  }

  __syncthreads();

  if (t < 128) partials[(size_t)blockIdx.x * 128 + t] = sacc[t];

  // Copy out: 2 passes x 256 threads x 16B. Pixel = 128B (64ch) contiguous.
  #pragma unroll
  for (int j = 0; j < 2; ++j) {
    const int u = j * 256 + t;           // 16B unit index, 0..511
    int byte = u * 16;
    byte ^= ((u >> 3) & 7) << 4;
    const bfv8 v = *(const bfv8*)(obuf + byte);
    const int pix = u >> 3, py = pix >> 3, pxx = pix & 7;
    *(bfv8*)(outp + ((size_t)((b * HH + h0 + py) * WW + (w0 + pxx))) * CH +
             och * 64 + (u & 7) * 8) = v;
  }
}

// ---------------------------------------------------------------------------
// K-red: reduce partials[6272][128] -> st[256] (sum[128]|sq[128]).
// Block g covers och = (g>>3)&1; its 128 floats are [64 sums | 64 sqs] of
// channels och*64..och*64+63. 32 blocks x 256 thr.
__global__ __launch_bounds__(256)
void stat_reduce(const float* __restrict__ partials, float* __restrict__ st) {
  const int t = threadIdx.x;
  int och, idx;
  if (t < 128) { och = t >> 6; idx = t & 63; }            // sums
  else { const int c = t - 128; och = c >> 6; idx = 64 + (c & 63); }  // sqs
  float s = 0.0f;
  const int i0 = blockIdx.x * (NCONVBLK / 32);
  for (int k = 0; k < NCONVBLK / 32; ++k) {
    const int i = i0 + k;                 // (q, xcd) pair index, 0..3135
    const int g = ((i >> 3) << 4) | (och << 3) | (i & 7);
    s += partials[(size_t)g * 128 + idx];
  }
  atomicAdd(&st[t], s);
}

// ---------------------------------------------------------------------------
// K4/K6: per-channel BN stats -> scale/shift tables.
__global__ __launch_bounds__(128)
void bn_stats(const float* __restrict__ st, const float* __restrict__ gamma,
              const float* __restrict__ beta, float* __restrict__ tab) {
  const int c = threadIdx.x;
  const float inv = 1.0f / NPIXF;
  const float mean = st[c] * inv;
  const float var = st[CH + c] * inv - mean * mean;
  const float s = gamma[c] / sqrtf(var + 1e-5f);
  tab[c] = s;
  tab[CH + c] = beta[c] - mean * s;
}

// ---------------------------------------------------------------------------
// K7: out = relu(scale2*y2 + shift2 + residual), NHWC bf16 -> NCHW fp32.
// BF16RES: residual from xT (bf16 NHWC, 51MB) instead of x (fp32 NCHW, 205MB).
template<bool BF16RES>
__global__ __launch_bounds__(256)
void final_kernel(const unsigned short* __restrict__ y2,
                  const unsigned short* __restrict__ xbf,
                  const float* __restrict__ x,
                  const float* __restrict__ tab, float* __restrict__ out) {
  const int bid = blockIdx.x;
  const int b = bid / 14, hq = bid % 14;
  const int h = hq * 4 + (threadIdx.x >> 6);
  const int w = threadIdx.x & 63;
  if (w >= WW) return;
  const unsigned short* ys = y2 + ((size_t)(b * HH + h) * WW + w) * CH;
  const unsigned short* rs = xbf + ((size_t)(b * HH + h) * WW + w) * CH;
  const float* xs = x + (size_t)b * CH * HWPIX + h * WW + w;
  float* os = out + (size_t)b * CH * HWPIX + h * WW + w;
  #pragma unroll 4
  for (int c = 0; c < CH; ++c) {
    const float v = bf2f(ys[c]);
    const float res = BF16RES ? bf2f(rs[c]) : xs[(size_t)c * HWPIX];
    const float r = v * tab[c] + tab[CH + c] + res;
    os[(size_t)c * HWPIX] = fmaxf(r, 0.0f);
  }
}

// ---------------------------------------------------------------------------
extern "C" void kernel_launch(void* const* d_in, const int* in_sizes, int n_in,
                              void* d_out, int out_size, void* d_ws, size_t ws_size,
                              hipStream_t stream) {
  const float* x  = (const float*)d_in[0];
  const float* w1 = (const float*)d_in[1];
  const float* w2 = (const float*)d_in[2];
  const float* g1 = (const float*)d_in[3];
  const float* b1 = (const float*)d_in[4];
  const float* g2 = (const float*)d_in[5];
  const float* b2 = (const float*)d_in[6];
  float* out = (float*)d_out;

  // Workspace layout (bytes):
  //   xT   0            51,380,224
  //   y1   51,380,224   51,380,224
  //   w1b  102,760,448  18,874,368
  //   w2b  121,634,816  18,874,368
  //   p1   140,509,184  3,211,264   (6272 x 128 floats)
  //   p2   143,720,448  3,211,264
  //   st   146,931,712  4,096   (st1|st2|tab1|tab2, 256 floats each)
  //   y2   146,935,808  51,380,224  (optional, if ws_size allows)
  char* ws = (char*)d_ws;
  unsigned short* xT  = (unsigned short*)(ws);
  unsigned short* y1  = (unsigned short*)(ws + 51380224);
  unsigned short* w1b = (unsigned short*)(ws + 102760448);
  unsigned short* w2b = (unsigned short*)(ws + 121634816);
  float*          p1  = (float*)(ws + 140509184);
  float*          p2  = (float*)(ws + 143720448);
  float*          st  = (float*)(ws + 146931712);
  const bool sepY2 = ws_size >= (size_t)146935808 + 51380224;
  unsigned short* y2  = sepY2 ? (unsigned short*)(ws + 146935808) : xT;

  (void)hipMemsetAsync(st, 0, 2048, stream);  // zero st1+st2

  hipLaunchKernelGGL(prep_x, dim3(NB * 14), dim3(256), 0, stream, x, xT);
  hipLaunchKernelGGL(prep_w, dim3(1024), dim3(256), 0, stream, w1, w2, w1b, w2b);
  hipLaunchKernelGGL((conv_kernel<false>), dim3(NCONVGRID), dim3(256), 0, stream,
                     xT, w1b, y1, p1, (const float*)nullptr);
  hipLaunchKernelGGL(stat_reduce, dim3(32), dim3(256), 0, stream, p1, st);
  hipLaunchKernelGGL(bn_stats, dim3(1), dim3(128), 0, stream, st, g1, b1, st + 512);
  hipLaunchKernelGGL((conv_kernel<true>), dim3(NCONVGRID), dim3(256), 0, stream,
                     y1, w2b, y2, p2, st + 512);
  hipLaunchKernelGGL(stat_reduce, dim3(32), dim3(256), 0, stream, p2, st + 256);
  hipLaunchKernelGGL(bn_stats, dim3(1), dim3(128), 0, stream, st + 256, g2, b2, st + 768);
  if (sepY2) {
    hipLaunchKernelGGL((final_kernel<true>), dim3(NB * 14), dim3(256), 0, stream,
                       y2, xT, x, st + 768, out);
  } else {
    hipLaunchKernelGGL((final_kernel<false>), dim3(NB * 14), dim3(256), 0, stream,
                       y2, xT, x, st + 768, out);
  }
}

// Round 6
// 479.501 us; speedup vs baseline: 1.1945x; 1.0326x over previous
//
#include <hip/hip_runtime.h>
#include <hip/hip_bf16.h>
#include <stdint.h>
#include <stddef.h>

// Problem dims (fixed): B=64, C=128, H=W=56, 3x3 conv pad=1 stride=1.
#define CH 128
#define HH 56
#define WW 56
#define HWPIX (HH*WW)        // 3136
#define NB 64
#define NPIXF 200704.0f      // B*H*W
#define NCONVBLK 1792        // 64 samples x 28 tiles (14x8 px)

typedef __attribute__((ext_vector_type(8))) short short8v;    // 8 bf16 -> MFMA A/B frag
typedef __attribute__((ext_vector_type(8))) unsigned short bfv8;
typedef __attribute__((ext_vector_type(4))) unsigned short bfv4;
typedef __attribute__((ext_vector_type(4))) float f32x4;

__device__ __forceinline__ unsigned short f2bf(float f) {
  unsigned int u = __float_as_uint(f);
  u += 0x7fffu + ((u >> 16) & 1u);            // RNE
  return (unsigned short)(u >> 16);
}
__device__ __forceinline__ float bf2f(unsigned short s) {
  return __uint_as_float(((unsigned int)s) << 16);
}

// ---------------------------------------------------------------------------
// K1: x NCHW fp32 -> NHWC bf16 (LDS transpose, coalesced 16B/lane writes).
__global__ __launch_bounds__(256)
void prep_x(const float* __restrict__ x, unsigned short* __restrict__ xT) {
  __shared__ unsigned short tile[4 * 56 * 128];
  const int bid = blockIdx.x;
  const int b = bid / 14, hq = bid % 14;
  const int hl = threadIdx.x >> 6;
  const int h = hq * 4 + hl;
  const int w = threadIdx.x & 63;
  if (w < WW) {
    const float* src = x + (size_t)b * CH * HWPIX + h * WW + w;
    const int pos = hl * WW + w;
    #pragma unroll 4
    for (int c0 = 0; c0 < CH; c0 += 8) {
      bfv8 v;
      #pragma unroll
      for (int k = 0; k < 8; ++k) v[k] = f2bf(src[(size_t)(c0 + k) * HWPIX]);
      const int idx = (pos * CH + c0) ^ ((pos & 7) << 3);
      *(bfv8*)(tile + idx) = v;
    }
  }
  __syncthreads();
  unsigned short* out = xT + (size_t)(b * HH + hq * 4) * WW * CH;
  #pragma unroll
  for (int j = 0; j < 14; ++j) {
    const int u = j * 256 + threadIdx.x;
    const int idx = (u * 8) ^ (((u >> 4) & 7) << 3);
    *(bfv8*)(out + u * 8) = *(const bfv8*)(tile + idx);
  }
}

// ---------------------------------------------------------------------------
// K2: weights [B,O,I,3,3] fp32 -> [B,tap,O,I] bf16 (dense reads, 16B writes).
__global__ __launch_bounds__(256)
void prep_w(const float* __restrict__ w1, const float* __restrict__ w2,
            unsigned short* __restrict__ o1, unsigned short* __restrict__ o2) {
  __shared__ unsigned short lw[18432];
  const int id = blockIdx.x;
  const int which = id >> 9;
  const int b = (id >> 3) & 63, ck = id & 7;
  const float* src = (which ? w2 : w1) + ((size_t)b * 16384 + ck * 2048) * 9;
  unsigned short* dst = (which ? o2 : o1);
  const int t = threadIdx.x;
  #pragma unroll
  for (int j = 0; j < 72; ++j)
    lw[j * 256 + t] = f2bf(src[j * 256 + t]);
  __syncthreads();
  const int ol = t >> 4, oct = t & 15;
  #pragma unroll
  for (int tap = 0; tap < 9; ++tap) {
    bfv8 v;
    #pragma unroll
    for (int k = 0; k < 8; ++k) v[k] = lw[(ol * 128 + oct * 8 + k) * 9 + tap];
    *(bfv8*)(dst + ((size_t)(b * 9 + tap) * CH + ck * 16 + ol) * CH + oct * 8) = v;
  }
}

// ---------------------------------------------------------------------------
// K3/K5: per-sample conv, implicit GEMM.
// R14: BIGGER PIXEL TILE. Occupancy-first is falsified both ways: forcing a
// smaller reg budget spills (R10/R11/R12: FETCH 34->129-205MB = fatal), and
// buying occupancy via O-split duplicated staging (R13: 2x blocks, MfmaUtil
// 12.9, conv 187us, WRITE 2x). At 2 waves/SIMD no pipe >25%: time is
// per-stage load->MFMA stall + per-block overheads. So amortize: tile 8x8 ->
// 14x8 (112 px), same 4-wave x 32-Och structure. Per half-tap: 28 MFMA vs 16
// (1.75x latency cover); blocks 3136->1792; per-block weight traffic (294KB)
// amortized over 1.75x px. acc[2][7]=56 regs (+24 -> ~204 combined < 256
// budget, no spill). LDS 44.5KB -> still 2 blocks/CU at (256,2).
// Predict: VGPR 140-190, FETCH 35-40MB WRITE ~53MB (FETCH>60MB = spill =
// abort), occ ~15-21 (not chasing), MfmaUtil 20-26, conv 110-135us.
template<bool FUSE>
__global__ __launch_bounds__(256, 2)
void conv_kernel(const unsigned short* __restrict__ in,
                 const unsigned short* __restrict__ wt,
                 unsigned short* __restrict__ outp,
                 float* __restrict__ partials,
                 const float* __restrict__ tab) {   // [256]: scale | shift (FUSE)
  __shared__ unsigned short patch[160 * 136];       // 16 h-rows x 10 w x 128ch
  __shared__ float sacc[256];                       // sum[128] | sumsq[128]
  const int xcd = blockIdx.x & 7;
  const int q = blockIdx.x >> 3;                    // 0..223
  const int s = q / 28;
  const int tile = q - s * 28;                      // 0..27
  const int b = s * 8 + xcd;
  const int ty = tile / 7, tx = tile % 7;
  const int h0 = ty * 14, w0 = tx * 8;
  const int t = threadIdx.x;

  const int lane = t & 63, wv = t >> 6;
  const int lrow = lane & 15, lgrp = lane >> 4;
  const int px = lrow & 7, pyl = lrow >> 3;

  sacc[t] = 0.0f;

  // A: lane holds W[o = wv*32 + mf*16 + lrow][k]; half I covers k-chunk
  // (I%2)*64 + {0,32} for rows lrow and lrow+16.
  const unsigned short* wbase =
      wt + (size_t)b * 9 * CH * CH + (wv * 32 + lrow) * CH + lgrp * 8;

  short8v b0[4], b1[4];
#define LOAD_HALF(dst, I) { \
    const unsigned short* wtap_ = wbase + ((I) / 2) * CH * CH + ((I) % 2) * 64; \
    _Pragma("unroll") \
    for (int c2 = 0; c2 < 2; ++c2) { \
      dst[c2 * 2 + 0] = *(const short8v*)(wtap_ + c2 * 32); \
      dst[c2 * 2 + 1] = *(const short8v*)(wtap_ + 16 * CH + c2 * 32); \
    } }

  // Head start: first two halves in flight before/through the staging barrier.
  LOAD_HALF(b0, 0)
  LOAD_HALF(b1, 1)

  // Staging: 160 rows x 2 halves of 64ch = 320 items; 256 threads, 2 passes.
  #pragma unroll
  for (int u = t; u < 320; u += 256) {
    const int row = u >> 1, half = u & 1;
    const int dh = row / 10, dw = row - dh * 10;
    const int h = h0 + dh - 1, w = w0 + dw - 1;
    unsigned short* ld = &patch[row * 136 + half * 64];
    if (h >= 0 && h < HH && w >= 0 && w < WW) {
      const unsigned short* src = in + ((size_t)((b * HH + h) * WW + w)) * CH + half * 64;
      if (FUSE) {
        #pragma unroll
        for (int j = 0; j < 8; ++j) {
          const bfv8 v = *(const bfv8*)(src + j * 8);
          bfv8 o;
          #pragma unroll
          for (int k = 0; k < 8; ++k) {
            const int c = half * 64 + j * 8 + k;
            const float f = fmaxf(bf2f(v[k]) * tab[c] + tab[CH + c], 0.0f);
            o[k] = f2bf(f);
          }
          *(bfv8*)(ld + j * 8) = o;
        }
      } else {
        #pragma unroll
        for (int j = 0; j < 8; ++j)
          *(bfv8*)(ld + j * 8) = *(const bfv8*)(src + j * 8);
      }
    } else {
      const bfv8 z = {0, 0, 0, 0, 0, 0, 0, 0};
      #pragma unroll
      for (int j = 0; j < 8; ++j) *(bfv8*)(ld + j * 8) = z;
    }
  }
  __syncthreads();

  f32x4 acc[2][7];
  #pragma unroll
  for (int m = 0; m < 2; ++m)
    #pragma unroll
    for (int n = 0; n < 7; ++n) acc[m][n] = (f32x4){0.f, 0.f, 0.f, 0.f};

#define MFMA_HALF(src, I) { \
    const int posb_ = (pyl + ((I) / 2) / 3) * 10 + px + ((I) / 2) % 3; \
    _Pragma("unroll") \
    for (int c2 = 0; c2 < 2; ++c2) { \
      _Pragma("unroll") \
      for (int nf = 0; nf < 7; ++nf) { \
        const short8v bfr = \
            *(const short8v*)(&patch[(posb_ + nf * 20) * 136 + (((I) % 2) * 2 + c2) * 32 + lgrp * 8]); \
        acc[0][nf] = __builtin_amdgcn_mfma_f32_16x16x32_bf16(src[c2 * 2 + 0], bfr, acc[0][nf], 0, 0, 0); \
        acc[1][nf] = __builtin_amdgcn_mfma_f32_16x16x32_bf16(src[c2 * 2 + 1], bfr, acc[1][nf], 0, 0, 0); \
      } } }

  // 18 half-taps, depth-1 lookahead over 2 rotating buffers.
  MFMA_HALF(b0,  0) LOAD_HALF(b0,  2)
  MFMA_HALF(b1,  1) LOAD_HALF(b1,  3)
  MFMA_HALF(b0,  2) LOAD_HALF(b0,  4)
  MFMA_HALF(b1,  3) LOAD_HALF(b1,  5)
  MFMA_HALF(b0,  4) LOAD_HALF(b0,  6)
  MFMA_HALF(b1,  5) LOAD_HALF(b1,  7)
  MFMA_HALF(b0,  6) LOAD_HALF(b0,  8)
  MFMA_HALF(b1,  7) LOAD_HALF(b1,  9)
  MFMA_HALF(b0,  8) LOAD_HALF(b0, 10)
  MFMA_HALF(b1,  9) LOAD_HALF(b1, 11)
  MFMA_HALF(b0, 10) LOAD_HALF(b0, 12)
  MFMA_HALF(b1, 11) LOAD_HALF(b1, 13)
  MFMA_HALF(b0, 12) LOAD_HALF(b0, 14)
  MFMA_HALF(b1, 13) LOAD_HALF(b1, 15)
  MFMA_HALF(b0, 14) LOAD_HALF(b0, 16)
  MFMA_HALF(b1, 15) LOAD_HALF(b1, 17)
  MFMA_HALF(b0, 16)
  MFMA_HALF(b1, 17)
#undef LOAD_HALF
#undef MFMA_HALF

  __syncthreads();   // patch reads done everywhere; reuse patch as output buffer

  // Stage D into LDS: obuf[pixel p 0..111][ch 0..127] bf16, byte ^= swizzle.
  char* obuf = (char*)patch;
  #pragma unroll
  for (int mf = 0; mf < 2; ++mf) {
    #pragma unroll
    for (int nf = 0; nf < 7; ++nf) {
      const f32x4 v = acc[mf][nf];
      bfv4 pk;
      #pragma unroll
      for (int r = 0; r < 4; ++r) pk[r] = f2bf(v[r]);
      const int p = (nf * 2 + pyl) * 8 + px;
      const int ch = wv * 32 + mf * 16 + lgrp * 4;
      int byte = p * 256 + ch * 2;
      byte ^= ((byte >> 8) & 3) << 5;
      *(bfv4*)(obuf + byte) = pk;
    }
  }

  // Fused BN stat partials: shuffle-reduce over the 16 pixel lanes,
  // LDS-accumulate, then ONE non-atomic 256-float row per block.
  #pragma unroll
  for (int mf = 0; mf < 2; ++mf) {
    f32x4 sv4 = {0.f, 0.f, 0.f, 0.f}, qv4 = {0.f, 0.f, 0.f, 0.f};
    #pragma unroll
    for (int nf = 0; nf < 7; ++nf) {
      const f32x4 v = acc[mf][nf];
      sv4 += v;
      qv4 += v * v;
    }
    #pragma unroll
    for (int r = 0; r < 4; ++r) {
      float sv = sv4[r], qv = qv4[r];
      sv += __shfl_xor(sv, 1, 64);  qv += __shfl_xor(qv, 1, 64);
      sv += __shfl_xor(sv, 2, 64);  qv += __shfl_xor(qv, 2, 64);
      sv += __shfl_xor(sv, 4, 64);  qv += __shfl_xor(qv, 4, 64);
      sv += __shfl_xor(sv, 8, 64);  qv += __shfl_xor(qv, 8, 64);
      if (lrow == 0) {
        const int ch = wv * 32 + mf * 16 + lgrp * 4 + r;
        atomicAdd(&sacc[ch], sv);        // LDS atomic, 8 per thread-group
        atomicAdd(&sacc[CH + ch], qv);
      }
    }
  }

  __syncthreads();

  partials[(size_t)blockIdx.x * 256 + t] = sacc[t];

  // Copy out: 7 passes x 256 threads x 16B, contiguous per wave.
  #pragma unroll
  for (int j = 0; j < 7; ++j) {
    const int u = j * 256 + t;           // 16B unit index, 0..1791
    int byte = u * 16;
    byte ^= ((byte >> 8) & 3) << 5;
    const bfv8 v = *(const bfv8*)(obuf + byte);
    const int pix = u >> 4, py = pix >> 3, pxx = pix & 7;
    *(bfv8*)(outp + ((size_t)((b * HH + h0 + py) * WW + (w0 + pxx))) * CH +
             (u & 15) * 8) = v;
  }
}

// ---------------------------------------------------------------------------
// K-red: reduce partials[1792][256] -> st[256]. 32 blocks x 256 thr.
__global__ __launch_bounds__(256)
void stat_reduce(const float* __restrict__ partials, float* __restrict__ st) {
  const int t = threadIdx.x;
  float s = 0.0f;
  const int i0 = blockIdx.x * (NCONVBLK / 32);
  for (int i = 0; i < NCONVBLK / 32; ++i)
    s += partials[(size_t)(i0 + i) * 256 + t];
  atomicAdd(&st[t], s);
}

// ---------------------------------------------------------------------------
// K4/K6: per-channel BN stats -> scale/shift tables.
__global__ __launch_bounds__(128)
void bn_stats(const float* __restrict__ st, const float* __restrict__ gamma,
              const float* __restrict__ beta, float* __restrict__ tab) {
  const int c = threadIdx.x;
  const float inv = 1.0f / NPIXF;
  const float mean = st[c] * inv;
  const float var = st[CH + c] * inv - mean * mean;
  const float s = gamma[c] / sqrtf(var + 1e-5f);
  tab[c] = s;
  tab[CH + c] = beta[c] - mean * s;
}

// ---------------------------------------------------------------------------
// K7: out = relu(scale2*y2 + shift2 + residual), NHWC bf16 -> NCHW fp32.
// BF16RES: residual from xT (bf16 NHWC, 51MB) instead of x (fp32 NCHW, 205MB).
template<bool BF16RES>
__global__ __launch_bounds__(256)
void final_kernel(const unsigned short* __restrict__ y2,
                  const unsigned short* __restrict__ xbf,
                  const float* __restrict__ x,
                  const float* __restrict__ tab, float* __restrict__ out) {
  const int bid = blockIdx.x;
  const int b = bid / 14, hq = bid % 14;
  const int h = hq * 4 + (threadIdx.x >> 6);
  const int w = threadIdx.x & 63;
  if (w >= WW) return;
  const unsigned short* ys = y2 + ((size_t)(b * HH + h) * WW + w) * CH;
  const unsigned short* rs = xbf + ((size_t)(b * HH + h) * WW + w) * CH;
  const float* xs = x + (size_t)b * CH * HWPIX + h * WW + w;
  float* os = out + (size_t)b * CH * HWPIX + h * WW + w;
  #pragma unroll 4
  for (int c = 0; c < CH; ++c) {
    const float v = bf2f(ys[c]);
    const float res = BF16RES ? bf2f(rs[c]) : xs[(size_t)c * HWPIX];
    const float r = v * tab[c] + tab[CH + c] + res;
    os[(size_t)c * HWPIX] = fmaxf(r, 0.0f);
  }
}

// ---------------------------------------------------------------------------
extern "C" void kernel_launch(void* const* d_in, const int* in_sizes, int n_in,
                              void* d_out, int out_size, void* d_ws, size_t ws_size,
                              hipStream_t stream) {
  const float* x  = (const float*)d_in[0];
  const float* w1 = (const float*)d_in[1];
  const float* w2 = (const float*)d_in[2];
  const float* g1 = (const float*)d_in[3];
  const float* b1 = (const float*)d_in[4];
  const float* g2 = (const float*)d_in[5];
  const float* b2 = (const float*)d_in[6];
  float* out = (float*)d_out;

  // Workspace layout (bytes):
  //   xT   0            51,380,224
  //   y1   51,380,224   51,380,224
  //   w1b  102,760,448  18,874,368
  //   w2b  121,634,816  18,874,368
  //   p1   140,509,184  3,211,264   (1792 x 256 floats used)
  //   p2   143,720,448  3,211,264
  //   st   146,931,712  4,096   (st1|st2|tab1|tab2, 256 floats each)
  //   y2   146,935,808  51,380,224  (optional, if ws_size allows)
  char* ws = (char*)d_ws;
  unsigned short* xT  = (unsigned short*)(ws);
  unsigned short* y1  = (unsigned short*)(ws + 51380224);
  unsigned short* w1b = (unsigned short*)(ws + 102760448);
  unsigned short* w2b = (unsigned short*)(ws + 121634816);
  float*          p1  = (float*)(ws + 140509184);
  float*          p2  = (float*)(ws + 143720448);
  float*          st  = (float*)(ws + 146931712);
  const bool sepY2 = ws_size >= (size_t)146935808 + 51380224;
  unsigned short* y2  = sepY2 ? (unsigned short*)(ws + 146935808) : xT;

  (void)hipMemsetAsync(st, 0, 2048, stream);  // zero st1+st2

  hipLaunchKernelGGL(prep_x, dim3(NB * 14), dim3(256), 0, stream, x, xT);
  hipLaunchKernelGGL(prep_w, dim3(1024), dim3(256), 0, stream, w1, w2, w1b, w2b);
  hipLaunchKernelGGL((conv_kernel<false>), dim3(NCONVBLK), dim3(256), 0, stream,
                     xT, w1b, y1, p1, (const float*)nullptr);
  hipLaunchKernelGGL(stat_reduce, dim3(32), dim3(256), 0, stream, p1, st);
  hipLaunchKernelGGL(bn_stats, dim3(1), dim3(128), 0, stream, st, g1, b1, st + 512);
  hipLaunchKernelGGL((conv_kernel<true>), dim3(NCONVBLK), dim3(256), 0, stream,
                     y1, w2b, y2, p2, st + 512);
  hipLaunchKernelGGL(stat_reduce, dim3(32), dim3(256), 0, stream, p2, st + 256);
  hipLaunchKernelGGL(bn_stats, dim3(1), dim3(128), 0, stream, st + 256, g2, b2, st + 768);
  if (sepY2) {
    hipLaunchKernelGGL((final_kernel<true>), dim3(NB * 14), dim3(256), 0, stream,
                       y2, xT, x, st + 768, out);
  } else {
    hipLaunchKernelGGL((final_kernel<false>), dim3(NB * 14), dim3(256), 0, stream,
                       y2, xT, x, st + 768, out);
  }
}

// Round 8
// 440.626 us; speedup vs baseline: 1.2999x; 1.0882x over previous
//
#include <hip/hip_runtime.h>
#include <hip/hip_bf16.h>
#include <stdint.h>
#include <stddef.h>

// Problem dims (fixed): B=64, C=128, H=W=56, 3x3 conv pad=1 stride=1.
#define CH 128
#define HH 56
#define WW 56
#define HWPIX (HH*WW)        // 3136
#define NB 64
#define NPIXF 200704.0f      // B*H*W
#define NCONVBLK 3136        // 64 samples x 49 tiles (8x8 px)

typedef __attribute__((ext_vector_type(8))) short short8v;    // 8 bf16 -> MFMA A/B frag
typedef __attribute__((ext_vector_type(8))) unsigned short bfv8;
typedef __attribute__((ext_vector_type(4))) unsigned short bfv4;
typedef __attribute__((ext_vector_type(4))) float f32x4;

__device__ __forceinline__ unsigned short f2bf(float f) {
  unsigned int u = __float_as_uint(f);
  u += 0x7fffu + ((u >> 16) & 1u);            // RNE
  return (unsigned short)(u >> 16);
}
__device__ __forceinline__ float bf2f(unsigned short s) {
  return __uint_as_float(((unsigned int)s) << 16);
}

// ---------------------------------------------------------------------------
// K1: x NCHW fp32 -> NHWC bf16 (LDS transpose, coalesced 16B/lane writes).
__global__ __launch_bounds__(256)
void prep_x(const float* __restrict__ x, unsigned short* __restrict__ xT) {
  __shared__ unsigned short tile[4 * 56 * 128];
  const int bid = blockIdx.x;
  const int b = bid / 14, hq = bid % 14;
  const int hl = threadIdx.x >> 6;
  const int h = hq * 4 + hl;
  const int w = threadIdx.x & 63;
  if (w < WW) {
    const float* src = x + (size_t)b * CH * HWPIX + h * WW + w;
    const int pos = hl * WW + w;
    #pragma unroll 4
    for (int c0 = 0; c0 < CH; c0 += 8) {
      bfv8 v;
      #pragma unroll
      for (int k = 0; k < 8; ++k) v[k] = f2bf(src[(size_t)(c0 + k) * HWPIX]);
      const int idx = (pos * CH + c0) ^ ((pos & 7) << 3);
      *(bfv8*)(tile + idx) = v;
    }
  }
  __syncthreads();
  unsigned short* out = xT + (size_t)(b * HH + hq * 4) * WW * CH;
  #pragma unroll
  for (int j = 0; j < 14; ++j) {
    const int u = j * 256 + threadIdx.x;
    const int idx = (u * 8) ^ (((u >> 4) & 7) << 3);
    *(bfv8*)(out + u * 8) = *(const bfv8*)(tile + idx);
  }
}

// ---------------------------------------------------------------------------
// K2: weights [B,O,I,3,3] fp32 -> [B,tap,O,I] bf16 (dense reads, 16B writes).
__global__ __launch_bounds__(256)
void prep_w(const float* __restrict__ w1, const float* __restrict__ w2,
            unsigned short* __restrict__ o1, unsigned short* __restrict__ o2) {
  __shared__ unsigned short lw[18432];
  const int id = blockIdx.x;
  const int which = id >> 9;
  const int b = (id >> 3) & 63, ck = id & 7;
  const float* src = (which ? w2 : w1) + ((size_t)b * 16384 + ck * 2048) * 9;
  unsigned short* dst = (which ? o2 : o1);
  const int t = threadIdx.x;
  #pragma unroll
  for (int j = 0; j < 72; ++j)
    lw[j * 256 + t] = f2bf(src[j * 256 + t]);
  __syncthreads();
  const int ol = t >> 4, oct = t & 15;
  #pragma unroll
  for (int tap = 0; tap < 9; ++tap) {
    bfv8 v;
    #pragma unroll
    for (int k = 0; k < 8; ++k) v[k] = lw[(ol * 128 + oct * 8 + k) * 9 + tap];
    *(bfv8*)(dst + ((size_t)(b * 9 + tap) * CH + ck * 16 + ol) * CH + oct * 8) = v;
  }
}

// ---------------------------------------------------------------------------
// K3/K5: per-sample conv, implicit GEMM.
// R16: R15's async wave-private weight staging with the RACES CLOSED.
// R15 failed absmax 1.25 -- diagnosed: (1) WAR race: 2-buffer rotation put
// COMPUTE(S-1)'s ds_reads (~200cyc to drain) against STAGE(S+1)'s LDS write
// to the same buffer (~200-500cyc after issue) -> overlap under DS-pipe
// contention; (2) hipcc may hoist ds_reads above the inline-asm vmcnt wait
// (rule-18 hazard); (3) R15's A-read pattern was 8-way bank-degenerate.
// Fixes: 3-buffer rotation (WAR distance = 2 full stages); sched_barrier(0)
// before each STAGE and after each waitcnt (pins compute(S-1) < gll(S+1) <
// wait < compute(S)); per-lane global source = the lane's OWN A-frag so the
// LDS image is lane-linear (gll requirement) AND the compute read is
// base+lane*16 = canonical conflict-free.  Weights use 0 VGPRs -> declare
// (256,3) (arch budget ~85, natural need ~80 with buffers gone). LDS
// 27.2K patch + 1K sacc + 24K wbuf = 52.8KB -> 3 blocks/CU.
// Predict: VGPR 78-85 NO spill (FETCH ~35MB, WRITE ~54MB; inflation=abort),
// occ 30-38%, MfmaUtil 20-28, conv 105-130us.
template<bool FUSE>
__global__ __launch_bounds__(256, 3)
void conv_kernel(const unsigned short* __restrict__ in,
                 const unsigned short* __restrict__ wt,
                 unsigned short* __restrict__ outp,
                 float* __restrict__ partials,
                 const float* __restrict__ tab) {   // [256]: scale | shift (FUSE)
  __shared__ unsigned short patch[100 * 136];
  __shared__ float sacc[256];                       // sum[128] | sumsq[128]
  __shared__ unsigned short wbuf[12288];            // 4 waves x 3 bufs x 1024
  const int xcd = blockIdx.x & 7;
  const int q = blockIdx.x >> 3;                    // 0..391
  const int s = q / 49;
  const int tile = q - s * 49;
  const int b = s * 8 + xcd;
  const int ty = tile / 7, tx = tile % 7;
  const int h0 = ty * 8, w0 = tx * 8;
  const int t = threadIdx.x;

  const int lane = t & 63, wv = t >> 6;
  const int lrow = lane & 15, lgrp = lane >> 4;
  const int px = lrow & 7, pyl = lrow >> 3;

  sacc[t] = 0.0f;

  // Per-lane global source = this lane's A-frag: W[o=wv*32+lrow][lgrp*8..+8].
  // gll writes lane l's 16B at LDS base + l*16 -> image IS the frag layout.
  const unsigned short* wsrc =
      wt + (size_t)b * 9 * CH * CH + (wv * 32 + lrow) * CH + lgrp * 8;

  // STAGE(S,P): async-load stage S (tap=S>>2, ic=S&3; 32 O x 32 I = 2KB/wave)
  // into wave-private buffer P. instr0: O rows +0..15; instr1: +16..31.
#define STAGE(S, P) { \
    const unsigned short* g_ = wsrc + ((S) >> 2) * (CH * CH) + ((S) & 3) * 32; \
    unsigned short* l_ = wbuf + (wv * 3 + (P)) * 1024; \
    __builtin_amdgcn_global_load_lds( \
        (const __attribute__((address_space(1))) void*)g_, \
        (__attribute__((address_space(3))) void*)l_, 16, 0, 0); \
    __builtin_amdgcn_global_load_lds( \
        (const __attribute__((address_space(1))) void*)(g_ + 16 * CH), \
        (__attribute__((address_space(3))) void*)(l_ + 512), 16, 0, 0); \
  }

  // Issue stage 0 before patch staging: latency hides under it; the
  // compiler's pre-barrier vmcnt(0) drain guarantees it resident after sync.
  STAGE(0, 0)

  if (t < 200) {                                    // 100 rows x 2 halves of 64ch
    const int row = t >> 1, half = t & 1;
    const int dh = row / 10, dw = row - dh * 10;
    const int h = h0 + dh - 1, w = w0 + dw - 1;
    unsigned short* ld = &patch[row * 136 + half * 64];
    if (h >= 0 && h < HH && w >= 0 && w < WW) {
      const unsigned short* src = in + ((size_t)((b * HH + h) * WW + w)) * CH + half * 64;
      if (FUSE) {
        #pragma unroll
        for (int j = 0; j < 8; ++j) {
          const bfv8 v = *(const bfv8*)(src + j * 8);
          bfv8 o;
          #pragma unroll
          for (int k = 0; k < 8; ++k) {
            const int c = half * 64 + j * 8 + k;
            const float f = fmaxf(bf2f(v[k]) * tab[c] + tab[CH + c], 0.0f);
            o[k] = f2bf(f);
          }
          *(bfv8*)(ld + j * 8) = o;
        }
      } else {
        #pragma unroll
        for (int j = 0; j < 8; ++j)
          *(bfv8*)(ld + j * 8) = *(const bfv8*)(src + j * 8);
      }
    } else {
      const bfv8 z = {0, 0, 0, 0, 0, 0, 0, 0};
      #pragma unroll
      for (int j = 0; j < 8; ++j) *(bfv8*)(ld + j * 8) = z;
    }
  }
  __syncthreads();

  f32x4 acc[2][4];
  #pragma unroll
  for (int m = 0; m < 2; ++m)
    #pragma unroll
    for (int n = 0; n < 4; ++n) acc[m][n] = (f32x4){0.f, 0.f, 0.f, 0.f};

  // COMPUTE(S,P): A-frags = lane-linear read of wave-private buf P
  // (conflict-free), B-frags from patch, 8 MFMA (K=32 chunk ic).
#define COMPUTE(S, P) { \
    const int tap_ = (S) >> 2, ic_ = (S) & 3; \
    const int posb_ = (pyl + tap_ / 3) * 10 + px + tap_ % 3; \
    const unsigned short* ab_ = wbuf + (wv * 3 + (P)) * 1024 + lane * 8; \
    const short8v a0_ = *(const short8v*)(ab_); \
    const short8v a1_ = *(const short8v*)(ab_ + 512); \
    _Pragma("unroll") \
    for (int nf = 0; nf < 4; ++nf) { \
      const short8v bfr = \
          *(const short8v*)(&patch[(posb_ + nf * 20) * 136 + ic_ * 32 + lgrp * 8]); \
      acc[0][nf] = __builtin_amdgcn_mfma_f32_16x16x32_bf16(a0_, bfr, acc[0][nf], 0, 0, 0); \
      acc[1][nf] = __builtin_amdgcn_mfma_f32_16x16x32_bf16(a1_, bfr, acc[1][nf], 0, 0, 0); \
    } }

  // RUN(S): [SB] issue S+1 -> wait vmcnt(2) (S resident, S+1 in flight)
  // [SB] compute S. sched_barrier(0) pins the order at compile time; the
  // 3-buffer rotation makes the WAR distance 2 full stages.
#define RUN(S) \
    __builtin_amdgcn_sched_barrier(0); \
    STAGE((S) + 1, ((S) + 1) % 3) \
    asm volatile("s_waitcnt vmcnt(2)" ::: "memory"); \
    __builtin_amdgcn_sched_barrier(0); \
    COMPUTE(S, (S) % 3)

  RUN(0)  RUN(1)  RUN(2)  RUN(3)  RUN(4)  RUN(5)  RUN(6)  RUN(7)
  RUN(8)  RUN(9)  RUN(10) RUN(11) RUN(12) RUN(13) RUN(14) RUN(15)
  RUN(16) RUN(17) RUN(18) RUN(19) RUN(20) RUN(21) RUN(22) RUN(23)
  RUN(24) RUN(25) RUN(26) RUN(27) RUN(28) RUN(29) RUN(30) RUN(31)
  RUN(32) RUN(33) RUN(34)
  __builtin_amdgcn_sched_barrier(0);
  asm volatile("s_waitcnt vmcnt(0)" ::: "memory");
  __builtin_amdgcn_sched_barrier(0);
  COMPUTE(35, 2)
#undef RUN
#undef COMPUTE
#undef STAGE

  __syncthreads();   // patch reads done everywhere; reuse patch as output buffer

  // Stage D into LDS: obuf[pixel p 0..63][ch 0..127] bf16, byte ^= ((p&3)<<5).
  char* obuf = (char*)patch;
  #pragma unroll
  for (int mf = 0; mf < 2; ++mf) {
    #pragma unroll
    for (int nf = 0; nf < 4; ++nf) {
      const f32x4 v = acc[mf][nf];
      bfv4 pk;
      #pragma unroll
      for (int r = 0; r < 4; ++r) pk[r] = f2bf(v[r]);
      const int p = (nf * 2 + pyl) * 8 + px;
      const int ch = wv * 32 + mf * 16 + lgrp * 4;
      int byte = p * 256 + ch * 2;
      byte ^= ((byte >> 8) & 3) << 5;
      *(bfv4*)(obuf + byte) = pk;
    }
  }

  // Fused BN stat partials: shuffle-reduce over the 16 pixel-col lanes,
  // LDS-accumulate, then ONE non-atomic 256-float row per block.
  #pragma unroll
  for (int mf = 0; mf < 2; ++mf) {
    f32x4 sv4 = {0.f, 0.f, 0.f, 0.f}, qv4 = {0.f, 0.f, 0.f, 0.f};
    #pragma unroll
    for (int nf = 0; nf < 4; ++nf) {
      const f32x4 v = acc[mf][nf];
      sv4 += v;
      qv4 += v * v;
    }
    #pragma unroll
    for (int r = 0; r < 4; ++r) {
      float sv = sv4[r], qv = qv4[r];
      sv += __shfl_xor(sv, 1, 64);  qv += __shfl_xor(qv, 1, 64);
      sv += __shfl_xor(sv, 2, 64);  qv += __shfl_xor(qv, 2, 64);
      sv += __shfl_xor(sv, 4, 64);  qv += __shfl_xor(qv, 4, 64);
      sv += __shfl_xor(sv, 8, 64);  qv += __shfl_xor(qv, 8, 64);
      if (lrow == 0) {
        const int ch = wv * 32 + mf * 16 + lgrp * 4 + r;
        atomicAdd(&sacc[ch], sv);        // LDS atomic, 8 per thread-group
        atomicAdd(&sacc[CH + ch], qv);
      }
    }
  }

  __syncthreads();

  partials[(size_t)blockIdx.x * 256 + t] = sacc[t];

  // Copy out: 4 passes x 256 threads x 16B, contiguous 1KB per wave.
  #pragma unroll
  for (int j = 0; j < 4; ++j) {
    const int u = j * 256 + t;           // 16B unit index, 0..1023
    int byte = u * 16;
    byte ^= ((byte >> 8) & 3) << 5;
    const bfv8 v = *(const bfv8*)(obuf + byte);
    const int pix = u >> 4, py = pix >> 3, pxx = pix & 7;
    *(bfv8*)(outp + ((size_t)((b * HH + h0 + py) * WW + (w0 + pxx))) * CH +
             (u & 15) * 8) = v;
  }
}

// ---------------------------------------------------------------------------
// K-red: reduce partials[3136][256] -> st[256]. 32 blocks x 256 thr.
__global__ __launch_bounds__(256)
void stat_reduce(const float* __restrict__ partials, float* __restrict__ st) {
  const int t = threadIdx.x;
  float s = 0.0f;
  const int i0 = blockIdx.x * (NCONVBLK / 32);
  for (int i = 0; i < NCONVBLK / 32; ++i)
    s += partials[(size_t)(i0 + i) * 256 + t];
  atomicAdd(&st[t], s);
}

// ---------------------------------------------------------------------------
// K4/K6: per-channel BN stats -> scale/shift tables.
__global__ __launch_bounds__(128)
void bn_stats(const float* __restrict__ st, const float* __restrict__ gamma,
              const float* __restrict__ beta, float* __restrict__ tab) {
  const int c = threadIdx.x;
  const float inv = 1.0f / NPIXF;
  const float mean = st[c] * inv;
  const float var = st[CH + c] * inv - mean * mean;
  const float s = gamma[c] / sqrtf(var + 1e-5f);
  tab[c] = s;
  tab[CH + c] = beta[c] - mean * s;
}

// ---------------------------------------------------------------------------
// K7: out = relu(scale2*y2 + shift2 + residual), NHWC bf16 -> NCHW fp32.
// BF16RES: residual from xT (bf16 NHWC, 51MB) instead of x (fp32 NCHW, 205MB).
template<bool BF16RES>
__global__ __launch_bounds__(256)
void final_kernel(const unsigned short* __restrict__ y2,
                  const unsigned short* __restrict__ xbf,
                  const float* __restrict__ x,
                  const float* __restrict__ tab, float* __restrict__ out) {
  const int bid = blockIdx.x;
  const int b = bid / 14, hq = bid % 14;
  const int h = hq * 4 + (threadIdx.x >> 6);
  const int w = threadIdx.x & 63;
  if (w >= WW) return;
  const unsigned short* ys = y2 + ((size_t)(b * HH + h) * WW + w) * CH;
  const unsigned short* rs = xbf + ((size_t)(b * HH + h) * WW + w) * CH;
  const float* xs = x + (size_t)b * CH * HWPIX + h * WW + w;
  float* os = out + (size_t)b * CH * HWPIX + h * WW + w;
  #pragma unroll 4
  for (int c = 0; c < CH; ++c) {
    const float v = bf2f(ys[c]);
    const float res = BF16RES ? bf2f(rs[c]) : xs[(size_t)c * HWPIX];
    const float r = v * tab[c] + tab[CH + c] + res;
    os[(size_t)c * HWPIX] = fmaxf(r, 0.0f);
  }
}

// ---------------------------------------------------------------------------
extern "C" void kernel_launch(void* const* d_in, const int* in_sizes, int n_in,
                              void* d_out, int out_size, void* d_ws, size_t ws_size,
                              hipStream_t stream) {
  const float* x  = (const float*)d_in[0];
  const float* w1 = (const float*)d_in[1];
  const float* w2 = (const float*)d_in[2];
  const float* g1 = (const float*)d_in[3];
  const float* b1 = (const float*)d_in[4];
  const float* g2 = (const float*)d_in[5];
  const float* b2 = (const float*)d_in[6];
  float* out = (float*)d_out;

  // Workspace layout (bytes):
  //   xT   0            51,380,224
  //   y1   51,380,224   51,380,224
  //   w1b  102,760,448  18,874,368
  //   w2b  121,634,816  18,874,368
  //   p1   140,509,184  3,211,264
  //   p2   143,720,448  3,211,264
  //   st   146,931,712  4,096   (st1|st2|tab1|tab2, 256 floats each)
  //   y2   146,935,808  51,380,224  (optional, if ws_size allows)
  char* ws = (char*)d_ws;
  unsigned short* xT  = (unsigned short*)(ws);
  unsigned short* y1  = (unsigned short*)(ws + 51380224);
  unsigned short* w1b = (unsigned short*)(ws + 102760448);
  unsigned short* w2b = (unsigned short*)(ws + 121634816);
  float*          p1  = (float*)(ws + 140509184);
  float*          p2  = (float*)(ws + 143720448);
  float*          st  = (float*)(ws + 146931712);
  const bool sepY2 = ws_size >= (size_t)146935808 + 51380224;
  unsigned short* y2  = sepY2 ? (unsigned short*)(ws + 146935808) : xT;

  (void)hipMemsetAsync(st, 0, 2048, stream);  // zero st1+st2

  hipLaunchKernelGGL(prep_x, dim3(NB * 14), dim3(256), 0, stream, x, xT);
  hipLaunchKernelGGL(prep_w, dim3(1024), dim3(256), 0, stream, w1, w2, w1b, w2b);
  hipLaunchKernelGGL((conv_kernel<false>), dim3(NCONVBLK), dim3(256), 0, stream,
                     xT, w1b, y1, p1, (const float*)nullptr);
  hipLaunchKernelGGL(stat_reduce, dim3(32), dim3(256), 0, stream, p1, st);
  hipLaunchKernelGGL(bn_stats, dim3(1), dim3(128), 0, stream, st, g1, b1, st + 512);
  hipLaunchKernelGGL((conv_kernel<true>), dim3(NCONVBLK), dim3(256), 0, stream,
                     y1, w2b, y2, p2, st + 512);
  hipLaunchKernelGGL(stat_reduce, dim3(32), dim3(256), 0, stream, p2, st + 256);
  hipLaunchKernelGGL(bn_stats, dim3(1), dim3(128), 0, stream, st + 256, g2, b2, st + 768);
  if (sepY2) {
    hipLaunchKernelGGL((final_kernel<true>), dim3(NB * 14), dim3(256), 0, stream,
                       y2, xT, x, st + 768, out);
  } else {
    hipLaunchKernelGGL((final_kernel<false>), dim3(NB * 14), dim3(256), 0, stream,
                       y2, xT, x, st + 768, out);
  }
}

// Round 9
// 430.879 us; speedup vs baseline: 1.3293x; 1.0226x over previous
//
#include <hip/hip_runtime.h>
#include <hip/hip_bf16.h>
#include <stdint.h>
#include <stddef.h>

// Problem dims (fixed): B=64, C=128, H=W=56, 3x3 conv pad=1 stride=1.
#define CH 128
#define HH 56
#define WW 56
#define HWPIX (HH*WW)        // 3136
#define NB 64
#define NPIXF 200704.0f      // B*H*W
#define NCONVBLK 3136        // 64 samples x 49 tiles (8x8 px)

typedef __attribute__((ext_vector_type(8))) short short8v;    // 8 bf16 -> MFMA A/B frag
typedef __attribute__((ext_vector_type(8))) unsigned short bfv8;
typedef __attribute__((ext_vector_type(4))) unsigned short bfv4;
typedef __attribute__((ext_vector_type(4))) float f32x4;

__device__ __forceinline__ unsigned short f2bf(float f) {
  unsigned int u = __float_as_uint(f);
  u += 0x7fffu + ((u >> 16) & 1u);            // RNE
  return (unsigned short)(u >> 16);
}
__device__ __forceinline__ float bf2f(unsigned short s) {
  return __uint_as_float(((unsigned int)s) << 16);
}

// ---------------------------------------------------------------------------
// K1: x NCHW fp32 -> NHWC bf16 (LDS transpose, coalesced 16B/lane writes).
__global__ __launch_bounds__(256)
void prep_x(const float* __restrict__ x, unsigned short* __restrict__ xT) {
  __shared__ unsigned short tile[4 * 56 * 128];
  const int bid = blockIdx.x;
  const int b = bid / 14, hq = bid % 14;
  const int hl = threadIdx.x >> 6;
  const int h = hq * 4 + hl;
  const int w = threadIdx.x & 63;
  if (w < WW) {
    const float* src = x + (size_t)b * CH * HWPIX + h * WW + w;
    const int pos = hl * WW + w;
    #pragma unroll 4
    for (int c0 = 0; c0 < CH; c0 += 8) {
      bfv8 v;
      #pragma unroll
      for (int k = 0; k < 8; ++k) v[k] = f2bf(src[(size_t)(c0 + k) * HWPIX]);
      const int idx = (pos * CH + c0) ^ ((pos & 7) << 3);
      *(bfv8*)(tile + idx) = v;
    }
  }
  __syncthreads();
  unsigned short* out = xT + (size_t)(b * HH + hq * 4) * WW * CH;
  #pragma unroll
  for (int j = 0; j < 14; ++j) {
    const int u = j * 256 + threadIdx.x;
    const int idx = (u * 8) ^ (((u >> 4) & 7) << 3);
    *(bfv8*)(out + u * 8) = *(const bfv8*)(tile + idx);
  }
}

// ---------------------------------------------------------------------------
// K2: weights [B,O,I,3,3] fp32 -> [B,tap,O,I] bf16 (dense reads, 16B writes).
__global__ __launch_bounds__(256)
void prep_w(const float* __restrict__ w1, const float* __restrict__ w2,
            unsigned short* __restrict__ o1, unsigned short* __restrict__ o2) {
  __shared__ unsigned short lw[18432];
  const int id = blockIdx.x;
  const int which = id >> 9;
  const int b = (id >> 3) & 63, ck = id & 7;
  const float* src = (which ? w2 : w1) + ((size_t)b * 16384 + ck * 2048) * 9;
  unsigned short* dst = (which ? o2 : o1);
  const int t = threadIdx.x;
  #pragma unroll
  for (int j = 0; j < 72; ++j)
    lw[j * 256 + t] = f2bf(src[j * 256 + t]);
  __syncthreads();
  const int ol = t >> 4, oct = t & 15;
  #pragma unroll
  for (int tap = 0; tap < 9; ++tap) {
    bfv8 v;
    #pragma unroll
    for (int k = 0; k < 8; ++k) v[k] = lw[(ol * 128 + oct * 8 + k) * 9 + tap];
    *(bfv8*)(dst + ((size_t)(b * 9 + tap) * CH + ck * 16 + ol) * CH + oct * 8) = v;
  }
}

// ---------------------------------------------------------------------------
// K3/K5: per-sample conv, implicit GEMM.
// R17: DEPTH-2 ASYNC PIPELINE. R16 (correct, no spill, occ 21->31%) proved
// occupancy is NOT the lever: +50% TLP -> +1.3%. The stall is correlated
// across waves: depth-1 vmcnt(2) lookahead (~110 issue-cyc of one COMPUTE)
// < gll L2 round-trip (~200-400cyc), so EVERY wave stalls at EVERY stage.
// Fix: 2 stages in flight -- issue S+2, wait vmcnt(4) (S resident, S+1/S+2
// in flight), compute S. Lookahead = 2 COMPUTEs (~250-300cyc) >= latency.
// 3-buffer rotation already supports it; WAR: STAGE(S+2) overwrites buffer
// compute(S-1) read, DMA write lands >=200cyc after those ds_reads queued
// (same margin class as R16; absmax fail = revert). Zero resource cost.
// Predict (theory): conv 153->120-135, MfmaUtil 15.7->19-23. Pre-committed
// null reading: conv +-5us => latency-depth falsified, limiter is a shared
// throughput resource (gll DMA rate / DS pipe+conflicts) -> next round cuts
// DS volume per FLOP (32x32 MFMA), not waits.
template<bool FUSE>
__global__ __launch_bounds__(256, 3)
void conv_kernel(const unsigned short* __restrict__ in,
                 const unsigned short* __restrict__ wt,
                 unsigned short* __restrict__ outp,
                 float* __restrict__ partials,
                 const float* __restrict__ tab) {   // [256]: scale | shift (FUSE)
  __shared__ unsigned short patch[100 * 136];
  __shared__ float sacc[256];                       // sum[128] | sumsq[128]
  __shared__ unsigned short wbuf[12288];            // 4 waves x 3 bufs x 1024
  const int xcd = blockIdx.x & 7;
  const int q = blockIdx.x >> 3;                    // 0..391
  const int s = q / 49;
  const int tile = q - s * 49;
  const int b = s * 8 + xcd;
  const int ty = tile / 7, tx = tile % 7;
  const int h0 = ty * 8, w0 = tx * 8;
  const int t = threadIdx.x;

  const int lane = t & 63, wv = t >> 6;
  const int lrow = lane & 15, lgrp = lane >> 4;
  const int px = lrow & 7, pyl = lrow >> 3;

  sacc[t] = 0.0f;

  // Per-lane global source = this lane's A-frag: W[o=wv*32+lrow][lgrp*8..+8].
  // gll writes lane l's 16B at LDS base + l*16 -> image IS the frag layout.
  const unsigned short* wsrc =
      wt + (size_t)b * 9 * CH * CH + (wv * 32 + lrow) * CH + lgrp * 8;

  // STAGE(S,P): async-load stage S (tap=S>>2, ic=S&3; 32 O x 32 I = 2KB/wave)
  // into wave-private buffer P. instr0: O rows +0..15; instr1: +16..31.
#define STAGE(S, P) { \
    const unsigned short* g_ = wsrc + ((S) >> 2) * (CH * CH) + ((S) & 3) * 32; \
    unsigned short* l_ = wbuf + (wv * 3 + (P)) * 1024; \
    __builtin_amdgcn_global_load_lds( \
        (const __attribute__((address_space(1))) void*)g_, \
        (__attribute__((address_space(3))) void*)l_, 16, 0, 0); \
    __builtin_amdgcn_global_load_lds( \
        (const __attribute__((address_space(1))) void*)(g_ + 16 * CH), \
        (__attribute__((address_space(3))) void*)(l_ + 512), 16, 0, 0); \
  }

  // Issue stage 0 before patch staging: latency hides under it; the
  // compiler's pre-barrier vmcnt(0) drain guarantees it resident after sync.
  STAGE(0, 0)

  if (t < 200) {                                    // 100 rows x 2 halves of 64ch
    const int row = t >> 1, half = t & 1;
    const int dh = row / 10, dw = row - dh * 10;
    const int h = h0 + dh - 1, w = w0 + dw - 1;
    unsigned short* ld = &patch[row * 136 + half * 64];
    if (h >= 0 && h < HH && w >= 0 && w < WW) {
      const unsigned short* src = in + ((size_t)((b * HH + h) * WW + w)) * CH + half * 64;
      if (FUSE) {
        #pragma unroll
        for (int j = 0; j < 8; ++j) {
          const bfv8 v = *(const bfv8*)(src + j * 8);
          bfv8 o;
          #pragma unroll
          for (int k = 0; k < 8; ++k) {
            const int c = half * 64 + j * 8 + k;
            const float f = fmaxf(bf2f(v[k]) * tab[c] + tab[CH + c], 0.0f);
            o[k] = f2bf(f);
          }
          *(bfv8*)(ld + j * 8) = o;
        }
      } else {
        #pragma unroll
        for (int j = 0; j < 8; ++j)
          *(bfv8*)(ld + j * 8) = *(const bfv8*)(src + j * 8);
      }
    } else {
      const bfv8 z = {0, 0, 0, 0, 0, 0, 0, 0};
      #pragma unroll
      for (int j = 0; j < 8; ++j) *(bfv8*)(ld + j * 8) = z;
    }
  }
  __syncthreads();

  f32x4 acc[2][4];
  #pragma unroll
  for (int m = 0; m < 2; ++m)
    #pragma unroll
    for (int n = 0; n < 4; ++n) acc[m][n] = (f32x4){0.f, 0.f, 0.f, 0.f};

  // Refill the pipeline after the barrier drain: stage 1 in flight now.
  STAGE(1, 1)

  // COMPUTE(S,P): A-frags = lane-linear read of wave-private buf P
  // (conflict-free), B-frags from patch, 8 MFMA (K=32 chunk ic).
#define COMPUTE(S, P) { \
    const int tap_ = (S) >> 2, ic_ = (S) & 3; \
    const int posb_ = (pyl + tap_ / 3) * 10 + px + tap_ % 3; \
    const unsigned short* ab_ = wbuf + (wv * 3 + (P)) * 1024 + lane * 8; \
    const short8v a0_ = *(const short8v*)(ab_); \
    const short8v a1_ = *(const short8v*)(ab_ + 512); \
    _Pragma("unroll") \
    for (int nf = 0; nf < 4; ++nf) { \
      const short8v bfr = \
          *(const short8v*)(&patch[(posb_ + nf * 20) * 136 + ic_ * 32 + lgrp * 8]); \
      acc[0][nf] = __builtin_amdgcn_mfma_f32_16x16x32_bf16(a0_, bfr, acc[0][nf], 0, 0, 0); \
      acc[1][nf] = __builtin_amdgcn_mfma_f32_16x16x32_bf16(a1_, bfr, acc[1][nf], 0, 0, 0); \
    } }

  // RUN(S): [SB] issue S+2 -> wait vmcnt(4) (S resident; S+1,S+2 in flight)
  // [SB] compute S. Depth-2: lookahead = 2 full COMPUTEs (~250-300cyc).
#define RUN(S) \
    __builtin_amdgcn_sched_barrier(0); \
    STAGE((S) + 2, ((S) + 2) % 3) \
    asm volatile("s_waitcnt vmcnt(4)" ::: "memory"); \
    __builtin_amdgcn_sched_barrier(0); \
    COMPUTE(S, (S) % 3)

  RUN(0)  RUN(1)  RUN(2)  RUN(3)  RUN(4)  RUN(5)  RUN(6)  RUN(7)
  RUN(8)  RUN(9)  RUN(10) RUN(11) RUN(12) RUN(13) RUN(14) RUN(15)
  RUN(16) RUN(17) RUN(18) RUN(19) RUN(20) RUN(21) RUN(22) RUN(23)
  RUN(24) RUN(25) RUN(26) RUN(27) RUN(28) RUN(29) RUN(30) RUN(31)
  RUN(32) RUN(33)
  // Tail: stages 34,35 already in flight.
  __builtin_amdgcn_sched_barrier(0);
  asm volatile("s_waitcnt vmcnt(2)" ::: "memory");
  __builtin_amdgcn_sched_barrier(0);
  COMPUTE(34, 1)
  __builtin_amdgcn_sched_barrier(0);
  asm volatile("s_waitcnt vmcnt(0)" ::: "memory");
  __builtin_amdgcn_sched_barrier(0);
  COMPUTE(35, 2)
#undef RUN
#undef COMPUTE
#undef STAGE

  __syncthreads();   // patch reads done everywhere; reuse patch as output buffer

  // Stage D into LDS: obuf[pixel p 0..63][ch 0..127] bf16, byte ^= ((p&3)<<5).
  char* obuf = (char*)patch;
  #pragma unroll
  for (int mf = 0; mf < 2; ++mf) {
    #pragma unroll
    for (int nf = 0; nf < 4; ++nf) {
      const f32x4 v = acc[mf][nf];
      bfv4 pk;
      #pragma unroll
      for (int r = 0; r < 4; ++r) pk[r] = f2bf(v[r]);
      const int p = (nf * 2 + pyl) * 8 + px;
      const int ch = wv * 32 + mf * 16 + lgrp * 4;
      int byte = p * 256 + ch * 2;
      byte ^= ((byte >> 8) & 3) << 5;
      *(bfv4*)(obuf + byte) = pk;
    }
  }

  // Fused BN stat partials: shuffle-reduce over the 16 pixel-col lanes,
  // LDS-accumulate, then ONE non-atomic 256-float row per block.
  #pragma unroll
  for (int mf = 0; mf < 2; ++mf) {
    f32x4 sv4 = {0.f, 0.f, 0.f, 0.f}, qv4 = {0.f, 0.f, 0.f, 0.f};
    #pragma unroll
    for (int nf = 0; nf < 4; ++nf) {
      const f32x4 v = acc[mf][nf];
      sv4 += v;
      qv4 += v * v;
    }
    #pragma unroll
    for (int r = 0; r < 4; ++r) {
      float sv = sv4[r], qv = qv4[r];
      sv += __shfl_xor(sv, 1, 64);  qv += __shfl_xor(qv, 1, 64);
      sv += __shfl_xor(sv, 2, 64);  qv += __shfl_xor(qv, 2, 64);
      sv += __shfl_xor(sv, 4, 64);  qv += __shfl_xor(qv, 4, 64);
      sv += __shfl_xor(sv, 8, 64);  qv += __shfl_xor(qv, 8, 64);
      if (lrow == 0) {
        const int ch = wv * 32 + mf * 16 + lgrp * 4 + r;
        atomicAdd(&sacc[ch], sv);        // LDS atomic, 8 per thread-group
        atomicAdd(&sacc[CH + ch], qv);
      }
    }
  }

  __syncthreads();

  partials[(size_t)blockIdx.x * 256 + t] = sacc[t];

  // Copy out: 4 passes x 256 threads x 16B, contiguous 1KB per wave.
  #pragma unroll
  for (int j = 0; j < 4; ++j) {
    const int u = j * 256 + t;           // 16B unit index, 0..1023
    int byte = u * 16;
    byte ^= ((byte >> 8) & 3) << 5;
    const bfv8 v = *(const bfv8*)(obuf + byte);
    const int pix = u >> 4, py = pix >> 3, pxx = pix & 7;
    *(bfv8*)(outp + ((size_t)((b * HH + h0 + py) * WW + (w0 + pxx))) * CH +
             (u & 15) * 8) = v;
  }
}

// ---------------------------------------------------------------------------
// K-red: reduce partials[3136][256] -> st[256]. 32 blocks x 256 thr.
__global__ __launch_bounds__(256)
void stat_reduce(const float* __restrict__ partials, float* __restrict__ st) {
  const int t = threadIdx.x;
  float s = 0.0f;
  const int i0 = blockIdx.x * (NCONVBLK / 32);
  for (int i = 0; i < NCONVBLK / 32; ++i)
    s += partials[(size_t)(i0 + i) * 256 + t];
  atomicAdd(&st[t], s);
}

// ---------------------------------------------------------------------------
// K4/K6: per-channel BN stats -> scale/shift tables.
__global__ __launch_bounds__(128)
void bn_stats(const float* __restrict__ st, const float* __restrict__ gamma,
              const float* __restrict__ beta, float* __restrict__ tab) {
  const int c = threadIdx.x;
  const float inv = 1.0f / NPIXF;
  const float mean = st[c] * inv;
  const float var = st[CH + c] * inv - mean * mean;
  const float s = gamma[c] / sqrtf(var + 1e-5f);
  tab[c] = s;
  tab[CH + c] = beta[c] - mean * s;
}

// ---------------------------------------------------------------------------
// K7: out = relu(scale2*y2 + shift2 + residual), NHWC bf16 -> NCHW fp32.
// BF16RES: residual from xT (bf16 NHWC, 51MB) instead of x (fp32 NCHW, 205MB).
template<bool BF16RES>
__global__ __launch_bounds__(256)
void final_kernel(const unsigned short* __restrict__ y2,
                  const unsigned short* __restrict__ xbf,
                  const float* __restrict__ x,
                  const float* __restrict__ tab, float* __restrict__ out) {
  const int bid = blockIdx.x;
  const int b = bid / 14, hq = bid % 14;
  const int h = hq * 4 + (threadIdx.x >> 6);
  const int w = threadIdx.x & 63;
  if (w >= WW) return;
  const unsigned short* ys = y2 + ((size_t)(b * HH + h) * WW + w) * CH;
  const unsigned short* rs = xbf + ((size_t)(b * HH + h) * WW + w) * CH;
  const float* xs = x + (size_t)b * CH * HWPIX + h * WW + w;
  float* os = out + (size_t)b * CH * HWPIX + h * WW + w;
  #pragma unroll 4
  for (int c = 0; c < CH; ++c) {
    const float v = bf2f(ys[c]);
    const float res = BF16RES ? bf2f(rs[c]) : xs[(size_t)c * HWPIX];
    const float r = v * tab[c] + tab[CH + c] + res;
    os[(size_t)c * HWPIX] = fmaxf(r, 0.0f);
  }
}

// ---------------------------------------------------------------------------
extern "C" void kernel_launch(void* const* d_in, const int* in_sizes, int n_in,
                              void* d_out, int out_size, void* d_ws, size_t ws_size,
                              hipStream_t stream) {
  const float* x  = (const float*)d_in[0];
  const float* w1 = (const float*)d_in[1];
  const float* w2 = (const float*)d_in[2];
  const float* g1 = (const float*)d_in[3];
  const float* b1 = (const float*)d_in[4];
  const float* g2 = (const float*)d_in[5];
  const float* b2 = (const float*)d_in[6];
  float* out = (float*)d_out;

  // Workspace layout (bytes):
  //   xT   0            51,380,224
  //   y1   51,380,224   51,380,224
  //   w1b  102,760,448  18,874,368
  //   w2b  121,634,816  18,874,368
  //   p1   140,509,184  3,211,264
  //   p2   143,720,448  3,211,264
  //   st   146,931,712  4,096   (st1|st2|tab1|tab2, 256 floats each)
  //   y2   146,935,808  51,380,224  (optional, if ws_size allows)
  char* ws = (char*)d_ws;
  unsigned short* xT  = (unsigned short*)(ws);
  unsigned short* y1  = (unsigned short*)(ws + 51380224);
  unsigned short* w1b = (unsigned short*)(ws + 102760448);
  unsigned short* w2b = (unsigned short*)(ws + 121634816);
  float*          p1  = (float*)(ws + 140509184);
  float*          p2  = (float*)(ws + 143720448);
  float*          st  = (float*)(ws + 146931712);
  const bool sepY2 = ws_size >= (size_t)146935808 + 51380224;
  unsigned short* y2  = sepY2 ? (unsigned short*)(ws + 146935808) : xT;

  (void)hipMemsetAsync(st, 0, 2048, stream);  // zero st1+st2

  hipLaunchKernelGGL(prep_x, dim3(NB * 14), dim3(256), 0, stream, x, xT);
  hipLaunchKernelGGL(prep_w, dim3(1024), dim3(256), 0, stream, w1, w2, w1b, w2b);
  hipLaunchKernelGGL((conv_kernel<false>), dim3(NCONVBLK), dim3(256), 0, stream,
                     xT, w1b, y1, p1, (const float*)nullptr);
  hipLaunchKernelGGL(stat_reduce, dim3(32), dim3(256), 0, stream, p1, st);
  hipLaunchKernelGGL(bn_stats, dim3(1), dim3(128), 0, stream, st, g1, b1, st + 512);
  hipLaunchKernelGGL((conv_kernel<true>), dim3(NCONVBLK), dim3(256), 0, stream,
                     y1, w2b, y2, p2, st + 512);
  hipLaunchKernelGGL(stat_reduce, dim3(32), dim3(256), 0, stream, p2, st + 256);
  hipLaunchKernelGGL(bn_stats, dim3(1), dim3(128), 0, stream, st + 256, g2, b2, st + 768);
  if (sepY2) {
    hipLaunchKernelGGL((final_kernel<true>), dim3(NB * 14), dim3(256), 0, stream,
                       y2, xT, x, st + 768, out);
  } else {
    hipLaunchKernelGGL((final_kernel<false>), dim3(NB * 14), dim3(256), 0, stream,
                       y2, xT, x, st + 768, out);
  }
}